// Round 6
// baseline (1443.306 us; speedup 1.0000x reference)
//
#include <hip/hip_runtime.h>
#include <stdint.h>

typedef __attribute__((ext_vector_type(4))) float f32x4;
typedef __attribute__((ext_vector_type(8))) short bf16x8;

__device__ __forceinline__ float bitsf(unsigned u) {
  union { unsigned u; float f; } x; x.u = u; return x.f;
}
__device__ __forceinline__ float b2f(unsigned short u) { return bitsf(((unsigned)u) << 16); }
__device__ __forceinline__ unsigned short f2b(float f) {
  union { float f; unsigned u; } x; x.f = f;
  unsigned r = x.u + 0x7FFFu + ((x.u >> 16) & 1u);
  return (unsigned short)(r >> 16);
}
__device__ __forceinline__ void async16(const void* g, void* l) {
  __builtin_amdgcn_global_load_lds((const __attribute__((address_space(1))) unsigned*)g,
                                   (__attribute__((address_space(3))) unsigned*)l, 16, 0, 0);
}
__device__ __forceinline__ void unpack8(uint4 u, float* f) {
  f[0] = bitsf(u.x << 16); f[1] = bitsf(u.x & 0xFFFF0000u);
  f[2] = bitsf(u.y << 16); f[3] = bitsf(u.y & 0xFFFF0000u);
  f[4] = bitsf(u.z << 16); f[5] = bitsf(u.z & 0xFFFF0000u);
  f[6] = bitsf(u.w << 16); f[7] = bitsf(u.w & 0xFFFF0000u);
}

// out[m,n] = relu?(acc+bias) (+residb bf16); A: MxK bf16 rm, B: NnxK bf16 rm.
// Round-4 structure: BK=32, 16KB LDS, grid (M/128 in .x, n-groups in .y).
// NL n-tiles per block: A re-staged per tile from same-XCD L2 (halves A HBM/L3 fetch).
// BN: fused per-channel sum/sumsq (rows < statN) into bns[0..511]/bns[512..1023].
template <bool BN>
__global__ __launch_bounds__(256) void gemm_bt(
    const unsigned short* __restrict__ A, const unsigned short* __restrict__ B,
    const float* __restrict__ bias, int relu,
    const unsigned short* __restrict__ residb,
    unsigned short* __restrict__ outb,
    float* __restrict__ bns, int statN,
    int Nn, int K, int NL)
{
  __shared__ __attribute__((aligned(16))) unsigned short As[128 * 32];
  __shared__ __attribute__((aligned(16))) unsigned short Bs[128 * 32];
  const int tid = threadIdx.x;
  const int lane = tid & 63;
  const int wave = tid >> 6;
  const int m0 = blockIdx.x * 128;
  const int wm = (wave & 1) * 64, wn = (wave >> 1) * 64;
  const int lr = lane & 15, lq = lane >> 4;

  // staging: wave w owns chunks 2w,2w+1 (16 rows x 4 col-blocks each).
  // lane i -> row rloc=i>>2, slot i&3; fetches global col-block (i&3)^((rloc>>1)&3).
  const int rloc = lane >> 2;
  const int gsw = (lane & 3) ^ ((rloc >> 1) & 3);
  const int rA0 = 32 * wave + rloc, rA1 = rA0 + 16;
  const unsigned short* gA0 = A + (size_t)(m0 + rA0) * K + gsw * 8;
  const unsigned short* gA1 = A + (size_t)(m0 + rA1) * K + gsw * 8;
  char* lA0 = (char*)As + wave * 2048;  // wave-uniform; HW adds lane*16
  char* lB0 = (char*)Bs + wave * 2048;
  const int pos8 = (lq ^ ((lr >> 1) & 3)) << 3;  // read slot swizzle

  for (int nt = 0; nt < NL; nt++) {
    const int n0 = (blockIdx.y * NL + nt) * 128;
    const unsigned short* gB0 = B + (size_t)(n0 + rA0) * K + gsw * 8;
    const unsigned short* gB1 = B + (size_t)(n0 + rA1) * K + gsw * 8;

    f32x4 acc[4][4];
#pragma unroll
    for (int i = 0; i < 4; i++)
#pragma unroll
      for (int j = 0; j < 4; j++) acc[i][j] = (f32x4){0.f, 0.f, 0.f, 0.f};

    for (int k0 = 0; k0 < K; k0 += 32) {
      async16(gA0 + k0, lA0);
      async16(gA1 + k0, lA0 + 1024);
      async16(gB0 + k0, lB0);
      async16(gB1 + k0, lB0 + 1024);
      __syncthreads();  // vmcnt(0) drain -> LDS visible

      bf16x8 af[4], bfr[4];
#pragma unroll
      for (int mi = 0; mi < 4; mi++)
        af[mi] = *(const bf16x8*)&As[(wm + mi * 16 + lr) * 32 + pos8];
#pragma unroll
      for (int ni = 0; ni < 4; ni++)
        bfr[ni] = *(const bf16x8*)&Bs[(wn + ni * 16 + lr) * 32 + pos8];
#pragma unroll
      for (int mi = 0; mi < 4; mi++)
#pragma unroll
        for (int ni = 0; ni < 4; ni++)
          acc[mi][ni] = __builtin_amdgcn_mfma_f32_16x16x32_bf16(af[mi], bfr[ni], acc[mi][ni], 0, 0, 0);
      __syncthreads();  // reads done before next overwrite
    }

    // D elem: m = wm+mi*16+lq*4+r, n = wn+ni*16+lr (m89/m91-verified C/D layout)
    float sn[4] = {0, 0, 0, 0}, qn[4] = {0, 0, 0, 0};
#pragma unroll
    for (int mi = 0; mi < 4; mi++) {
#pragma unroll
      for (int r = 0; r < 4; r++) {
        int gm = m0 + wm + mi * 16 + lq * 4 + r;
        size_t base = (size_t)gm * Nn;
#pragma unroll
        for (int ni = 0; ni < 4; ni++) {
          int gn = n0 + wn + ni * 16 + lr;
          float v = acc[mi][ni][r];
          if (bias) v += bias[gn];
          if (relu) v = fmaxf(v, 0.f);
          if (residb) v += b2f(residb[base + gn]);
          outb[base + gn] = f2b(v);
          if (BN && gm < statN) { sn[ni] += v; qn[ni] += v * v; }
        }
      }
    }
    if (BN) {
#pragma unroll
      for (int ni = 0; ni < 4; ni++) {
        float s = sn[ni], q = qn[ni];
        s += __shfl_xor(s, 16, 64); q += __shfl_xor(q, 16, 64);
        s += __shfl_xor(s, 32, 64); q += __shfl_xor(q, 32, 64);
        if (lq == 0) {
          int gn = n0 + wn + ni * 16 + lr;
          atomicAdd(&bns[gn], s);
          atomicAdd(&bns[512 + gn], q);
        }
      }
    }
  }
}

// ---------- CSR build ----------
__global__ void hist_k(const int* __restrict__ tgt, int* __restrict__ deg, int E) {
  for (int e = blockIdx.x * 256 + threadIdx.x; e < E; e += gridDim.x * 256)
    atomicAdd(&deg[tgt[e]], 1);
}

__global__ void scan_k(const int* __restrict__ deg, int* __restrict__ rowptr,
                       int* __restrict__ cursor, int n) {
  __shared__ int s[1024];
  __shared__ int carry;
  if (threadIdx.x == 0) carry = 0;
  __syncthreads();
  for (int base = 0; base < n; base += 1024) {
    int i = base + threadIdx.x;
    int x = (i < n) ? deg[i] : 0;
    s[threadIdx.x] = x;
    __syncthreads();
    for (int off = 1; off < 1024; off <<= 1) {
      int t = (threadIdx.x >= off) ? s[threadIdx.x - off] : 0;
      __syncthreads();
      s[threadIdx.x] += t;
      __syncthreads();
    }
    int incl = s[threadIdx.x];
    int cpre = carry;
    if (i < n) { rowptr[i] = cpre + incl - x; cursor[i] = cpre + incl - x; }
    __syncthreads();
    if (threadIdx.x == 1023) carry = cpre + s[1023];
    __syncthreads();
  }
  if (threadIdx.x == 0) rowptr[n] = carry;
}

__global__ void scatter_k(const int* __restrict__ srci, const int* __restrict__ tgt,
                          int* __restrict__ cursor, int* __restrict__ esrc, int E) {
  for (int e = blockIdx.x * 256 + threadIdx.x; e < E; e += gridDim.x * 256) {
    int pos = atomicAdd(&cursor[tgt[e]], 1);
    esrc[pos] = srci[e];
  }
}

// ---------- attention: one WAVE per target node; lane covers 8 channels; 8 lanes/head ----------
__global__ __launch_bounds__(256) void attn_k(
    const unsigned short* __restrict__ qkv, const int* __restrict__ rowptr,
    const int* __restrict__ esrc, unsigned short* __restrict__ aggb, int N)
{
  const int node = blockIdx.x * 4 + (threadIdx.x >> 6);
  const int lane = threadIdx.x & 63;
  if (node >= N) return;
  const int beg = rowptr[node], end = rowptr[node + 1];
  const uint4* qrow = (const uint4*)(qkv + (size_t)node * 1536);
  float qf[8];
  unpack8(qrow[lane], qf);
  float acc[8] = {0, 0, 0, 0, 0, 0, 0, 0};
  float ssum = 0.f;
  int i = beg;
  for (; i + 1 < end; i += 2) {
    int s0 = esrc[i], s1 = esrc[i + 1];
    const uint4* r0 = (const uint4*)(qkv + (size_t)s0 * 1536);
    const uint4* r1 = (const uint4*)(qkv + (size_t)s1 * 1536);
    uint4 k0 = r0[64 + lane], v0 = r0[128 + lane];
    uint4 k1 = r1[64 + lane], v1 = r1[128 + lane];
    float kf[8], vf[8];
    unpack8(k0, kf);
    float p0 = 0.f;
#pragma unroll
    for (int j = 0; j < 8; j++) p0 += qf[j] * kf[j];
    unpack8(k1, kf);
    float p1 = 0.f;
#pragma unroll
    for (int j = 0; j < 8; j++) p1 += qf[j] * kf[j];
#pragma unroll
    for (int off = 1; off < 8; off <<= 1) {
      p0 += __shfl_xor(p0, off, 64);
      p1 += __shfl_xor(p1, off, 64);
    }
    float w0 = __expf(p0), w1 = __expf(p1);
    ssum += w0 + w1;
    unpack8(v0, vf);
#pragma unroll
    for (int j = 0; j < 8; j++) acc[j] += w0 * vf[j];
    unpack8(v1, vf);
#pragma unroll
    for (int j = 0; j < 8; j++) acc[j] += w1 * vf[j];
  }
  if (i < end) {
    int s0 = esrc[i];
    const uint4* r0 = (const uint4*)(qkv + (size_t)s0 * 1536);
    uint4 k0 = r0[64 + lane], v0 = r0[128 + lane];
    float kf[8], vf[8];
    unpack8(k0, kf);
    float p0 = 0.f;
#pragma unroll
    for (int j = 0; j < 8; j++) p0 += qf[j] * kf[j];
#pragma unroll
    for (int off = 1; off < 8; off <<= 1) p0 += __shfl_xor(p0, off, 64);
    float w0 = __expf(p0);
    ssum += w0;
    unpack8(v0, vf);
#pragma unroll
    for (int j = 0; j < 8; j++) acc[j] += w0 * vf[j];
  }
  float inv = 1.0f / (ssum + 1e-16f);
  uint4 o;
  o.x = ((unsigned)f2b(acc[1] * inv) << 16) | f2b(acc[0] * inv);
  o.y = ((unsigned)f2b(acc[3] * inv) << 16) | f2b(acc[2] * inv);
  o.z = ((unsigned)f2b(acc[5] * inv) << 16) | f2b(acc[4] * inv);
  o.w = ((unsigned)f2b(acc[7] * inv) << 16) | f2b(acc[6] * inv);
  ((uint4*)(aggb + (size_t)node * 512))[lane] = o;
}

// ---------- batchnorm apply (stats fused into GEMM epilogue); all-bf16 ----------
__global__ void bn_apply_k(const unsigned short* __restrict__ tb, const float* __restrict__ bns,
                           const float* __restrict__ g, const float* __restrict__ be,
                           unsigned short* __restrict__ xb, int N, int NPAD) {
  __shared__ float sa[512], sb[512];
  for (int c = threadIdx.x; c < 512; c += 256) {
    float mu = bns[c] / (float)N;
    float var = bns[512 + c] / (float)N - mu * mu;
    float inv = rsqrtf(var + 1e-5f);
    float ga = g[c] * inv;
    sa[c] = ga;
    sb[c] = be[c] - mu * ga;
  }
  __syncthreads();
  size_t total = (size_t)NPAD * 512;
  for (size_t idx = (size_t)blockIdx.x * 256 + threadIdx.x; idx < total; idx += (size_t)gridDim.x * 256) {
    int r = (int)(idx >> 9);
    int c = (int)(idx & 511);
    float v = 0.f;
    if (r < N) v = b2f(tb[idx]) * sa[c] + sb[c];
    xb[idx] = f2b(v);
  }
}

// ---------- conversions ----------
__global__ void cvt_k(const float* __restrict__ in, unsigned short* __restrict__ out, size_t n) {
  for (size_t i = (size_t)blockIdx.x * 256 + threadIdx.x; i < n; i += (size_t)gridDim.x * 256)
    out[i] = f2b(in[i]);
}

// wqkv: [2][1536][512] bf16 (q rows prescaled by 0.125); bqkv: [2][1536] fp32
__global__ void build_qkvw_k(const float* __restrict__ Wq, const float* __restrict__ Wk,
                             const float* __restrict__ Wv, const float* __restrict__ bq,
                             unsigned short* __restrict__ wqkv, float* __restrict__ bqkv) {
  const size_t total = (size_t)2 * 1536 * 512;
  for (size_t idx = (size_t)blockIdx.x * 256 + threadIdx.x; idx < total; idx += (size_t)gridDim.x * 256) {
    int l = (int)(idx / (1536 * 512));
    int rem = (int)(idx % (1536 * 512));
    int rr = rem >> 9, c = rem & 511;
    float v;
    if (rr < 512)       v = Wq[(size_t)l * 262144 + rr * 512 + c] * 0.125f;
    else if (rr < 1024) v = Wk[(size_t)l * 262144 + (rr - 512) * 512 + c];
    else                v = Wv[(size_t)l * 262144 + (rr - 1024) * 512 + c];
    wqkv[idx] = f2b(v);
  }
  for (int i = blockIdx.x * 256 + threadIdx.x; i < 2 * 1536; i += gridDim.x * 256) {
    int l = i / 1536, rr = i % 1536;
    bqkv[i] = (rr < 512) ? bq[l * 512 + rr] * 0.125f : 0.f;
  }
}

__global__ void src_pad_k(const float* __restrict__ src, unsigned short* __restrict__ xb,
                          int N, int NPAD) {
  size_t total = (size_t)NPAD * 512;
  for (size_t i = (size_t)blockIdx.x * 256 + threadIdx.x; i < total; i += (size_t)gridDim.x * 256) {
    int r = (int)(i >> 9);
    xb[i] = (r < N) ? f2b(src[i]) : (unsigned short)0;
  }
}

__global__ __launch_bounds__(256) void ln_final_k(
    const unsigned short* __restrict__ xb, const float* __restrict__ g,
    const float* __restrict__ be, float* __restrict__ out, int N) {
  int row = blockIdx.x * 4 + (threadIdx.x >> 6);
  int lane = threadIdx.x & 63;
  if (row >= N) return;
  const uint4* xr = (const uint4*)(xb + (size_t)row * 512);
  float v[8];
  unpack8(xr[lane], v);
  float s = 0.f, q = 0.f;
#pragma unroll
  for (int j = 0; j < 8; j++) { s += v[j]; q += v[j] * v[j]; }
#pragma unroll
  for (int off = 32; off > 0; off >>= 1) { s += __shfl_xor(s, off, 64); q += __shfl_xor(q, off, 64); }
  float mu = s * (1.0f / 512.0f);
  float var = q * (1.0f / 512.0f) - mu * mu;
  float inv = rsqrtf(var + 1e-5f);
  float* orow = out + (size_t)row * 512;
#pragma unroll
  for (int j = 0; j < 8; j++) {
    int c = lane * 8 + j;
    orow[c] = (v[j] - mu) * inv * g[c] + be[c];
  }
}

// ---------- launch ----------
extern "C" void kernel_launch(void* const* d_in, const int* in_sizes, int n_in,
                              void* d_out, int out_size, void* d_ws, size_t ws_size,
                              hipStream_t stream)
{
  const float* src = (const float*)d_in[0];
  const int* eidx = (const int*)d_in[1];
  const float* Wq = (const float*)d_in[2];
  const float* bq = (const float*)d_in[3];
  const float* Wk = (const float*)d_in[4];
  const float* Wv = (const float*)d_in[5];
  const float* Wo = (const float*)d_in[6];
  const float* bo = (const float*)d_in[7];
  const float* W1 = (const float*)d_in[8];
  const float* b1 = (const float*)d_in[9];
  const float* W2 = (const float*)d_in[10];
  const float* b2 = (const float*)d_in[11];
  const float* g1 = (const float*)d_in[12];
  const float* be1 = (const float*)d_in[13];
  const float* g2 = (const float*)d_in[14];
  const float* be2 = (const float*)d_in[15];
  const float* lng = (const float*)d_in[16];
  const float* lnb = (const float*)d_in[17];

  const int N = in_sizes[0] / 512;
  const int E = in_sizes[1] / 2;
  const int NPAD = ((N + 127) / 128) * 128;

  char* w = (char*)d_ws;
  size_t off = 0;
  auto alloc = [&](size_t b) -> char* { char* p = w + off; off = (off + b + 255) & ~(size_t)255; return p; };
  // qkvb (NPAD x 1536) + aggb (NPAD x 512) contiguous => hb spans NPAD x 2048
  unsigned short* qkvb = (unsigned short*)alloc((size_t)NPAD * 1536 * 2);
  unsigned short* aggb = (unsigned short*)alloc((size_t)NPAD * 512 * 2);
  unsigned short* hb   = qkvb;  // FF hidden; qkv/agg dead by then
  unsigned short* xb   = (unsigned short*)alloc((size_t)NPAD * 512 * 2);
  unsigned short* tb   = (unsigned short*)alloc((size_t)NPAD * 512 * 2);  // pre-BN tmp
  unsigned short* wqkv = (unsigned short*)alloc((size_t)2 * 1536 * 512 * 2);
  float* bqkv          = (float*)alloc((size_t)2 * 1536 * 4);
  unsigned short* wWo = (unsigned short*)alloc((size_t)2 * 512 * 512 * 2);
  unsigned short* wW1 = (unsigned short*)alloc((size_t)2 * 2048 * 512 * 2);
  unsigned short* wW2 = (unsigned short*)alloc((size_t)2 * 512 * 2048 * 2);
  int* rowptr = (int*)alloc((size_t)(N + 1) * 4);
  int* cursor = (int*)alloc((size_t)N * 4);
  int* deg    = (int*)alloc((size_t)N * 4);
  int* esrc   = (int*)alloc((size_t)E * 4);
  float* bnsum = (float*)alloc(1024 * 4);
  (void)ws_size; (void)n_in; (void)out_size;

  const int* srci = eidx;
  const int* tgt  = eidx + E;

  hipMemsetAsync(deg, 0, (size_t)N * 4, stream);

  src_pad_k<<<2048, 256, 0, stream>>>(src, xb, N, NPAD);
  build_qkvw_k<<<1024, 256, 0, stream>>>(Wq, Wk, Wv, bq, wqkv, bqkv);
  cvt_k<<<1024, 256, 0, stream>>>(Wo, wWo, (size_t)2 * 512 * 512);
  cvt_k<<<1024, 256, 0, stream>>>(W1, wW1, (size_t)2 * 2048 * 512);
  cvt_k<<<1024, 256, 0, stream>>>(W2, wW2, (size_t)2 * 512 * 2048);
  hist_k<<<1250, 256, 0, stream>>>(tgt, deg, E);
  scan_k<<<1, 1024, 0, stream>>>(deg, rowptr, cursor, N);
  scatter_k<<<1250, 256, 0, stream>>>(srci, tgt, cursor, esrc, E);

  const int MT = NPAD / 128;
  for (int l = 0; l < 2; l++) {
    const unsigned short* Wqkv_l = wqkv + (size_t)l * 1536 * 512;
    const unsigned short* Wo_l = wWo + (size_t)l * 512 * 512;
    const unsigned short* W1_l = wW1 + (size_t)l * 2048 * 512;
    const unsigned short* W2_l = wW2 + (size_t)l * 512 * 2048;

    // QKV: Nn=1536, NL=2 -> grid (MT, 6)
    gemm_bt<false><<<dim3(MT, 6), 256, 0, stream>>>(
        xb, Wqkv_l, bqkv + l * 1536, 0, nullptr, qkvb, nullptr, 0, 1536, 512, 2);
    attn_k<<<(N + 3) / 4, 256, 0, stream>>>(qkvb, rowptr, esrc, aggb, N);
    hipMemsetAsync(bnsum, 0, 4096, stream);
    // Wo: resid=xb (layer input), out tb + fused BN stats
    gemm_bt<true><<<dim3(MT, 4), 256, 0, stream>>>(
        aggb, Wo_l, bo + l * 512, 0, xb, tb, bnsum, N, 512, 512, 1);
    bn_apply_k<<<2048, 256, 0, stream>>>(tb, bnsum, g1 + l * 512, be1 + l * 512, xb, N, NPAD);
    // FF1: Nn=2048, NL=2 -> grid (MT, 8), relu
    gemm_bt<false><<<dim3(MT, 8), 256, 0, stream>>>(
        xb, W1_l, b1 + l * 2048, 1, nullptr, hb, nullptr, 0, 2048, 512, 2);
    hipMemsetAsync(bnsum, 0, 4096, stream);
    // FF2: resid=xb (post-BN1), out tb + fused BN stats
    gemm_bt<true><<<dim3(MT, 4), 256, 0, stream>>>(
        hb, W2_l, b2 + l * 512, 0, xb, tb, bnsum, N, 512, 2048, 1);
    bn_apply_k<<<2048, 256, 0, stream>>>(tb, bnsum, g2 + l * 512, be2 + l * 512, xb, N, NPAD);
  }
  ln_final_k<<<(N + 3) / 4, 256, 0, stream>>>(xb, lng, lnb, (float*)d_out, N);
}

// Round 7
// 1132.207 us; speedup vs baseline: 1.2748x; 1.2748x over previous
//
#include <hip/hip_runtime.h>
#include <stdint.h>

typedef __attribute__((ext_vector_type(4))) float f32x4;
typedef __attribute__((ext_vector_type(8))) short bf16x8;

__device__ __forceinline__ float bitsf(unsigned u) {
  union { unsigned u; float f; } x; x.u = u; return x.f;
}
__device__ __forceinline__ float b2f(unsigned short u) { return bitsf(((unsigned)u) << 16); }
__device__ __forceinline__ unsigned short f2b(float f) {
  union { float f; unsigned u; } x; x.f = f;
  unsigned r = x.u + 0x7FFFu + ((x.u >> 16) & 1u);
  return (unsigned short)(r >> 16);
}
__device__ __forceinline__ void async16(const void* g, void* l) {
  __builtin_amdgcn_global_load_lds((const __attribute__((address_space(1))) unsigned*)g,
                                   (__attribute__((address_space(3))) unsigned*)l, 16, 0, 0);
}
__device__ __forceinline__ void unpack8(uint4 u, float* f) {
  f[0] = bitsf(u.x << 16); f[1] = bitsf(u.x & 0xFFFF0000u);
  f[2] = bitsf(u.y << 16); f[3] = bitsf(u.y & 0xFFFF0000u);
  f[4] = bitsf(u.z << 16); f[5] = bitsf(u.z & 0xFFFF0000u);
  f[6] = bitsf(u.w << 16); f[7] = bitsf(u.w & 0xFFFF0000u);
}

// out[m,n] = relu?(acc+bias) (+residb); A: MxK bf16 rm, B: NnxK bf16 rm.
// Round-4 body (BK=32, 16KB LDS). 1D grid with XCD swizzle: b -> xcd=b&7, slot=b>>3;
// y = slot % YT (fast), x = xcd*XCHUNK + slot/YT. All n-blocks of one A-tile share an XCD.
__global__ __launch_bounds__(256) void gemm_bt(
    const unsigned short* __restrict__ A, const unsigned short* __restrict__ B,
    const float* __restrict__ bias, int relu,
    const unsigned short* __restrict__ residb,
    unsigned short* __restrict__ outb,
    float* __restrict__ bns, int statN,
    int Nn, int K, int YT, int XCHUNK)
{
  __shared__ __attribute__((aligned(16))) unsigned short As[128 * 32];
  __shared__ __attribute__((aligned(16))) unsigned short Bs[128 * 32];
  const int b = blockIdx.x;
  const int slot = b >> 3;
  const int m0 = ((b & 7) * XCHUNK + slot / YT) * 128;
  const int n0 = (slot % YT) * 128;
  const int tid = threadIdx.x;
  const int lane = tid & 63;
  const int wave = tid >> 6;
  const int wm = (wave & 1) * 64, wn = (wave >> 1) * 64;
  const int lr = lane & 15, lq = lane >> 4;

  f32x4 acc[4][4];
#pragma unroll
  for (int i = 0; i < 4; i++)
#pragma unroll
    for (int j = 0; j < 4; j++) acc[i][j] = (f32x4){0.f, 0.f, 0.f, 0.f};

  // staging: wave w owns chunks 2w,2w+1 (16 rows x 4 col-blocks each).
  // lane i -> row rloc=i>>2, slot i&3; fetches global col-block (i&3)^((rloc>>1)&3).
  const int rloc = lane >> 2;
  const int gsw = (lane & 3) ^ ((rloc >> 1) & 3);
  const int rA0 = 32 * wave + rloc, rA1 = rA0 + 16;
  const unsigned short* gA0 = A + (size_t)(m0 + rA0) * K + gsw * 8;
  const unsigned short* gA1 = A + (size_t)(m0 + rA1) * K + gsw * 8;
  const unsigned short* gB0 = B + (size_t)(n0 + rA0) * K + gsw * 8;
  const unsigned short* gB1 = B + (size_t)(n0 + rA1) * K + gsw * 8;
  char* lA0 = (char*)As + wave * 2048;  // wave-uniform; HW adds lane*16
  char* lB0 = (char*)Bs + wave * 2048;
  const int pos8 = (lq ^ ((lr >> 1) & 3)) << 3;  // read slot swizzle

  for (int k0 = 0; k0 < K; k0 += 32) {
    async16(gA0 + k0, lA0);
    async16(gA1 + k0, lA0 + 1024);
    async16(gB0 + k0, lB0);
    async16(gB1 + k0, lB0 + 1024);
    __syncthreads();  // vmcnt(0) drain -> LDS visible

    bf16x8 af[4], bfr[4];
#pragma unroll
    for (int mi = 0; mi < 4; mi++)
      af[mi] = *(const bf16x8*)&As[(wm + mi * 16 + lr) * 32 + pos8];
#pragma unroll
    for (int ni = 0; ni < 4; ni++)
      bfr[ni] = *(const bf16x8*)&Bs[(wn + ni * 16 + lr) * 32 + pos8];
#pragma unroll
    for (int mi = 0; mi < 4; mi++)
#pragma unroll
      for (int ni = 0; ni < 4; ni++)
        acc[mi][ni] = __builtin_amdgcn_mfma_f32_16x16x32_bf16(af[mi], bfr[ni], acc[mi][ni], 0, 0, 0);
    __syncthreads();  // reads done before next overwrite
  }

  // D elem: m = wm+mi*16+lq*4+r, n = wn+ni*16+lr (m89/m91-verified C/D layout)
  float sn[4] = {0, 0, 0, 0}, qn[4] = {0, 0, 0, 0};
#pragma unroll
  for (int mi = 0; mi < 4; mi++) {
#pragma unroll
    for (int r = 0; r < 4; r++) {
      int gm = m0 + wm + mi * 16 + lq * 4 + r;
      size_t base = (size_t)gm * Nn;
#pragma unroll
      for (int ni = 0; ni < 4; ni++) {
        int gn = n0 + wn + ni * 16 + lr;
        float v = acc[mi][ni][r];
        if (bias) v += bias[gn];
        if (relu) v = fmaxf(v, 0.f);
        if (residb) v += b2f(residb[base + gn]);
        outb[base + gn] = f2b(v);
        if (bns && gm < statN) { sn[ni] += v; qn[ni] += v * v; }
      }
    }
  }
  if (bns) {
#pragma unroll
    for (int ni = 0; ni < 4; ni++) {
      float s = sn[ni], q = qn[ni];
      s += __shfl_xor(s, 16, 64); q += __shfl_xor(q, 16, 64);
      s += __shfl_xor(s, 32, 64); q += __shfl_xor(q, 32, 64);
      if (lq == 0) {
        int gn = n0 + wn + ni * 16 + lr;
        atomicAdd(&bns[gn], s);
        atomicAdd(&bns[512 + gn], q);
      }
    }
  }
}

// ---------- CSR build ----------
__global__ void hist_k(const int* __restrict__ tgt, int* __restrict__ deg, int E) {
  for (int e = blockIdx.x * 256 + threadIdx.x; e < E; e += gridDim.x * 256)
    atomicAdd(&deg[tgt[e]], 1);
}

__global__ void scan_k(const int* __restrict__ deg, int* __restrict__ rowptr,
                       int* __restrict__ cursor, int n) {
  __shared__ int s[1024];
  __shared__ int carry;
  if (threadIdx.x == 0) carry = 0;
  __syncthreads();
  for (int base = 0; base < n; base += 1024) {
    int i = base + threadIdx.x;
    int x = (i < n) ? deg[i] : 0;
    s[threadIdx.x] = x;
    __syncthreads();
    for (int off = 1; off < 1024; off <<= 1) {
      int t = (threadIdx.x >= off) ? s[threadIdx.x - off] : 0;
      __syncthreads();
      s[threadIdx.x] += t;
      __syncthreads();
    }
    int incl = s[threadIdx.x];
    int cpre = carry;
    if (i < n) { rowptr[i] = cpre + incl - x; cursor[i] = cpre + incl - x; }
    __syncthreads();
    if (threadIdx.x == 1023) carry = cpre + s[1023];
    __syncthreads();
  }
  if (threadIdx.x == 0) rowptr[n] = carry;
}

__global__ void scatter_k(const int* __restrict__ srci, const int* __restrict__ tgt,
                          int* __restrict__ cursor, int* __restrict__ esrc, int E) {
  for (int e = blockIdx.x * 256 + threadIdx.x; e < E; e += gridDim.x * 256) {
    int pos = atomicAdd(&cursor[tgt[e]], 1);
    esrc[pos] = srci[e];
  }
}

// ---------- attention: one WAVE per target node; lane covers 8 channels; 8 lanes/head ----------
__global__ __launch_bounds__(256) void attn_k(
    const unsigned short* __restrict__ qkv, const int* __restrict__ rowptr,
    const int* __restrict__ esrc, unsigned short* __restrict__ aggb, int N)
{
  const int node = blockIdx.x * 4 + (threadIdx.x >> 6);
  const int lane = threadIdx.x & 63;
  if (node >= N) return;
  const int beg = rowptr[node], end = rowptr[node + 1];
  const uint4* qrow = (const uint4*)(qkv + (size_t)node * 1536);
  float qf[8];
  unpack8(qrow[lane], qf);
  float acc[8] = {0, 0, 0, 0, 0, 0, 0, 0};
  float ssum = 0.f;
  int i = beg;
  for (; i + 1 < end; i += 2) {
    int s0 = esrc[i], s1 = esrc[i + 1];
    const uint4* r0 = (const uint4*)(qkv + (size_t)s0 * 1536);
    const uint4* r1 = (const uint4*)(qkv + (size_t)s1 * 1536);
    uint4 k0 = r0[64 + lane], v0 = r0[128 + lane];
    uint4 k1 = r1[64 + lane], v1 = r1[128 + lane];
    float kf[8], vf[8];
    unpack8(k0, kf);
    float p0 = 0.f;
#pragma unroll
    for (int j = 0; j < 8; j++) p0 += qf[j] * kf[j];
    unpack8(k1, kf);
    float p1 = 0.f;
#pragma unroll
    for (int j = 0; j < 8; j++) p1 += qf[j] * kf[j];
#pragma unroll
    for (int off = 1; off < 8; off <<= 1) {
      p0 += __shfl_xor(p0, off, 64);
      p1 += __shfl_xor(p1, off, 64);
    }
    float w0 = __expf(p0), w1 = __expf(p1);
    ssum += w0 + w1;
    unpack8(v0, vf);
#pragma unroll
    for (int j = 0; j < 8; j++) acc[j] += w0 * vf[j];
    unpack8(v1, vf);
#pragma unroll
    for (int j = 0; j < 8; j++) acc[j] += w1 * vf[j];
  }
  if (i < end) {
    int s0 = esrc[i];
    const uint4* r0 = (const uint4*)(qkv + (size_t)s0 * 1536);
    uint4 k0 = r0[64 + lane], v0 = r0[128 + lane];
    float kf[8], vf[8];
    unpack8(k0, kf);
    float p0 = 0.f;
#pragma unroll
    for (int j = 0; j < 8; j++) p0 += qf[j] * kf[j];
#pragma unroll
    for (int off = 1; off < 8; off <<= 1) p0 += __shfl_xor(p0, off, 64);
    float w0 = __expf(p0);
    ssum += w0;
    unpack8(v0, vf);
#pragma unroll
    for (int j = 0; j < 8; j++) acc[j] += w0 * vf[j];
  }
  float inv = 1.0f / (ssum + 1e-16f);
  uint4 o;
  o.x = ((unsigned)f2b(acc[1] * inv) << 16) | f2b(acc[0] * inv);
  o.y = ((unsigned)f2b(acc[3] * inv) << 16) | f2b(acc[2] * inv);
  o.z = ((unsigned)f2b(acc[5] * inv) << 16) | f2b(acc[4] * inv);
  o.w = ((unsigned)f2b(acc[7] * inv) << 16) | f2b(acc[6] * inv);
  ((uint4*)(aggb + (size_t)node * 512))[lane] = o;
}

// ---------- batchnorm apply (stats fused into GEMM epilogue); all-bf16 ----------
__global__ void bn_apply_k(const unsigned short* __restrict__ tb, const float* __restrict__ bns,
                           const float* __restrict__ g, const float* __restrict__ be,
                           unsigned short* __restrict__ xb, int N, int NPAD) {
  __shared__ float sa[512], sb[512];
  for (int c = threadIdx.x; c < 512; c += 256) {
    float mu = bns[c] / (float)N;
    float var = bns[512 + c] / (float)N - mu * mu;
    float inv = rsqrtf(var + 1e-5f);
    float ga = g[c] * inv;
    sa[c] = ga;
    sb[c] = be[c] - mu * ga;
  }
  __syncthreads();
  size_t total = (size_t)NPAD * 512;
  for (size_t idx = (size_t)blockIdx.x * 256 + threadIdx.x; idx < total; idx += (size_t)gridDim.x * 256) {
    int r = (int)(idx >> 9);
    int c = (int)(idx & 511);
    float v = 0.f;
    if (r < N) v = b2f(tb[idx]) * sa[c] + sb[c];
    xb[idx] = f2b(v);
  }
}

// ---------- conversions ----------
__global__ void cvt_k(const float* __restrict__ in, unsigned short* __restrict__ out, size_t n) {
  for (size_t i = (size_t)blockIdx.x * 256 + threadIdx.x; i < n; i += (size_t)gridDim.x * 256)
    out[i] = f2b(in[i]);
}

// wqkv: [2][1536][512] bf16 (q rows prescaled by 0.125); bqkv: [2][1536] fp32
__global__ void build_qkvw_k(const float* __restrict__ Wq, const float* __restrict__ Wk,
                             const float* __restrict__ Wv, const float* __restrict__ bq,
                             unsigned short* __restrict__ wqkv, float* __restrict__ bqkv) {
  const size_t total = (size_t)2 * 1536 * 512;
  for (size_t idx = (size_t)blockIdx.x * 256 + threadIdx.x; idx < total; idx += (size_t)gridDim.x * 256) {
    int l = (int)(idx / (1536 * 512));
    int rem = (int)(idx % (1536 * 512));
    int rr = rem >> 9, c = rem & 511;
    float v;
    if (rr < 512)       v = Wq[(size_t)l * 262144 + rr * 512 + c] * 0.125f;
    else if (rr < 1024) v = Wk[(size_t)l * 262144 + (rr - 512) * 512 + c];
    else                v = Wv[(size_t)l * 262144 + (rr - 1024) * 512 + c];
    wqkv[idx] = f2b(v);
  }
  for (int i = blockIdx.x * 256 + threadIdx.x; i < 2 * 1536; i += gridDim.x * 256) {
    int l = i / 1536, rr = i % 1536;
    bqkv[i] = (rr < 512) ? bq[l * 512 + rr] * 0.125f : 0.f;
  }
}

__global__ void src_pad_k(const float* __restrict__ src, unsigned short* __restrict__ xb,
                          int N, int NPAD) {
  size_t total = (size_t)NPAD * 512;
  for (size_t i = (size_t)blockIdx.x * 256 + threadIdx.x; i < total; i += (size_t)gridDim.x * 256) {
    int r = (int)(i >> 9);
    xb[i] = (r < N) ? f2b(src[i]) : (unsigned short)0;
  }
}

__global__ __launch_bounds__(256) void ln_final_k(
    const unsigned short* __restrict__ xb, const float* __restrict__ g,
    const float* __restrict__ be, float* __restrict__ out, int N) {
  int row = blockIdx.x * 4 + (threadIdx.x >> 6);
  int lane = threadIdx.x & 63;
  if (row >= N) return;
  const uint4* xr = (const uint4*)(xb + (size_t)row * 512);
  float v[8];
  unpack8(xr[lane], v);
  float s = 0.f, q = 0.f;
#pragma unroll
  for (int j = 0; j < 8; j++) { s += v[j]; q += v[j] * v[j]; }
#pragma unroll
  for (int off = 32; off > 0; off >>= 1) { s += __shfl_xor(s, off, 64); q += __shfl_xor(q, off, 64); }
  float mu = s * (1.0f / 512.0f);
  float var = q * (1.0f / 512.0f) - mu * mu;
  float inv = rsqrtf(var + 1e-5f);
  float* orow = out + (size_t)row * 512;
#pragma unroll
  for (int j = 0; j < 8; j++) {
    int c = lane * 8 + j;
    orow[c] = (v[j] - mu) * inv * g[c] + be[c];
  }
}

// ---------- launch ----------
extern "C" void kernel_launch(void* const* d_in, const int* in_sizes, int n_in,
                              void* d_out, int out_size, void* d_ws, size_t ws_size,
                              hipStream_t stream)
{
  const float* src = (const float*)d_in[0];
  const int* eidx = (const int*)d_in[1];
  const float* Wq = (const float*)d_in[2];
  const float* bq = (const float*)d_in[3];
  const float* Wk = (const float*)d_in[4];
  const float* Wv = (const float*)d_in[5];
  const float* Wo = (const float*)d_in[6];
  const float* bo = (const float*)d_in[7];
  const float* W1 = (const float*)d_in[8];
  const float* b1 = (const float*)d_in[9];
  const float* W2 = (const float*)d_in[10];
  const float* b2 = (const float*)d_in[11];
  const float* g1 = (const float*)d_in[12];
  const float* be1 = (const float*)d_in[13];
  const float* g2 = (const float*)d_in[14];
  const float* be2 = (const float*)d_in[15];
  const float* lng = (const float*)d_in[16];
  const float* lnb = (const float*)d_in[17];

  const int N = in_sizes[0] / 512;
  const int E = in_sizes[1] / 2;
  const int NPAD = ((N + 1023) / 1024) * 1024;  // m-tiles divisible by 8 (XCD swizzle)
  const int MT = NPAD / 128;
  const int XCHUNK = MT / 8;

  char* w = (char*)d_ws;
  size_t off = 0;
  auto alloc = [&](size_t b) -> char* { char* p = w + off; off = (off + b + 255) & ~(size_t)255; return p; };
  // qkvb (NPAD x 1536) + aggb (NPAD x 512) contiguous => hb spans NPAD x 2048
  unsigned short* qkvb = (unsigned short*)alloc((size_t)NPAD * 1536 * 2);
  unsigned short* aggb = (unsigned short*)alloc((size_t)NPAD * 512 * 2);
  unsigned short* hb   = qkvb;  // FF hidden; qkv/agg dead by then
  unsigned short* xb   = (unsigned short*)alloc((size_t)NPAD * 512 * 2);
  unsigned short* tb   = (unsigned short*)alloc((size_t)NPAD * 512 * 2);  // pre-BN tmp
  unsigned short* wqkv = (unsigned short*)alloc((size_t)2 * 1536 * 512 * 2);
  float* bqkv          = (float*)alloc((size_t)2 * 1536 * 4);
  unsigned short* wWo = (unsigned short*)alloc((size_t)2 * 512 * 512 * 2);
  unsigned short* wW1 = (unsigned short*)alloc((size_t)2 * 2048 * 512 * 2);
  unsigned short* wW2 = (unsigned short*)alloc((size_t)2 * 512 * 2048 * 2);
  int* rowptr = (int*)alloc((size_t)(N + 1) * 4);
  int* cursor = (int*)alloc((size_t)N * 4);
  int* deg    = (int*)alloc((size_t)N * 4);
  int* esrc   = (int*)alloc((size_t)E * 4);
  float* bnsum = (float*)alloc(1024 * 4);
  (void)ws_size; (void)n_in; (void)out_size;

  const int* srci = eidx;
  const int* tgt  = eidx + E;

  hipMemsetAsync(deg, 0, (size_t)N * 4, stream);

  src_pad_k<<<2048, 256, 0, stream>>>(src, xb, N, NPAD);
  build_qkvw_k<<<1024, 256, 0, stream>>>(Wq, Wk, Wv, bq, wqkv, bqkv);
  cvt_k<<<1024, 256, 0, stream>>>(Wo, wWo, (size_t)2 * 512 * 512);
  cvt_k<<<1024, 256, 0, stream>>>(W1, wW1, (size_t)2 * 2048 * 512);
  cvt_k<<<1024, 256, 0, stream>>>(W2, wW2, (size_t)2 * 512 * 2048);
  hist_k<<<1250, 256, 0, stream>>>(tgt, deg, E);
  scan_k<<<1, 1024, 0, stream>>>(deg, rowptr, cursor, N);
  scatter_k<<<1250, 256, 0, stream>>>(srci, tgt, cursor, esrc, E);

  for (int l = 0; l < 2; l++) {
    const unsigned short* Wqkv_l = wqkv + (size_t)l * 1536 * 512;
    const unsigned short* Wo_l = wWo + (size_t)l * 512 * 512;
    const unsigned short* W1_l = wW1 + (size_t)l * 2048 * 512;
    const unsigned short* W2_l = wW2 + (size_t)l * 512 * 2048;

    // QKV: Nn=1536, YT=12
    gemm_bt<<<MT * 12, 256, 0, stream>>>(
        xb, Wqkv_l, bqkv + l * 1536, 0, nullptr, qkvb, nullptr, 0, 1536, 512, 12, XCHUNK);
    attn_k<<<(N + 3) / 4, 256, 0, stream>>>(qkvb, rowptr, esrc, aggb, N);
    hipMemsetAsync(bnsum, 0, 4096, stream);
    // Wo: resid=xb (layer input), out tb + fused BN stats; YT=4
    gemm_bt<<<MT * 4, 256, 0, stream>>>(
        aggb, Wo_l, bo + l * 512, 0, xb, tb, bnsum, N, 512, 512, 4, XCHUNK);
    bn_apply_k<<<2048, 256, 0, stream>>>(tb, bnsum, g1 + l * 512, be1 + l * 512, xb, N, NPAD);
    // FF1: Nn=2048, YT=16, relu
    gemm_bt<<<MT * 16, 256, 0, stream>>>(
        xb, W1_l, b1 + l * 2048, 1, nullptr, hb, nullptr, 0, 2048, 512, 16, XCHUNK);
    hipMemsetAsync(bnsum, 0, 4096, stream);
    // FF2: K=2048, resid=xb (post-BN1), out tb + fused BN stats; YT=4
    gemm_bt<<<MT * 4, 256, 0, stream>>>(
        hb, W2_l, b2 + l * 512, 0, xb, tb, bnsum, N, 512, 2048, 4, XCHUNK);
    bn_apply_k<<<2048, 256, 0, stream>>>(tb, bnsum, g2 + l * 512, be2 + l * 512, xb, N, NPAD);
  }
  ln_final_k<<<(N + 3) / 4, 256, 0, stream>>>(xb, lng, lnb, (float*)d_out, N);
}